// Round 7
// baseline (168.012 us; speedup 1.0000x reference)
//
#include <hip/hip_runtime.h>

typedef _Float16 f16;
typedef __attribute__((ext_vector_type(4))) _Float16 f16x4;
typedef __attribute__((ext_vector_type(8))) _Float16 f16x8;
typedef __attribute__((ext_vector_type(4))) float f32x4;

#define MFMA16(a, b, c) __builtin_amdgcn_mfma_f32_16x16x32_f16((a), (b), (c), 0, 0, 0)

__device__ __forceinline__ void gload_lds16(const void* g, void* l) {
  __builtin_amdgcn_global_load_lds(
      (const __attribute__((address_space(1))) void*)g,
      (__attribute__((address_space(3))) void*)l, 16, 0, 0);
}

// ------- fused prep: convert x -> f16, transpose Wqkv & Wproj -> [N][K] f16 -------
__global__ __launch_bounds__(256) void k_prep(
    const float* __restrict__ x, f16* __restrict__ xb,
    const float* __restrict__ Wq, f16* __restrict__ WqT,
    const float* __restrict__ Wp, f16* __restrict__ WpT) {
  __shared__ float tile[64][65];
  int bid = blockIdx.x;
  if (bid < 768) {
    int i = bid * 256 + threadIdx.x;
#pragma unroll
    for (int it = 0; it < 4; ++it, i += 768 * 256) {
      float4 v = ((const float4*)x)[i];
      f16x4 o;
      o[0] = (f16)v.x; o[1] = (f16)v.y; o[2] = (f16)v.z; o[3] = (f16)v.w;
      ((f16x4*)xb)[i] = o;
    }
    return;
  }
  const float* in; f16* out; int N, n0, k0;
  if (bid < 1200) {
    int t = bid - 768;
    in = Wq; out = WqT; N = 2304;
    n0 = (t % 36) * 64; k0 = (t / 36) * 64;
  } else {
    int t = bid - 1200;
    in = Wp; out = WpT; N = 768;
    n0 = (t % 12) * 64; k0 = (t / 12) * 64;
  }
  int c = threadIdx.x & 63, r4 = threadIdx.x >> 6;
#pragma unroll
  for (int i = 0; i < 16; ++i) {
    int r = i * 4 + r4;
    tile[r][c] = in[(size_t)(k0 + r) * N + n0 + c];
  }
  __syncthreads();
#pragma unroll
  for (int i = 0; i < 16; ++i) {
    int r = i * 4 + r4;
    out[(size_t)(n0 + r) * 768 + k0 + c] = (f16)tile[c][r];
  }
}

// ---------------- 128x128 f16 MFMA GEMM, A[M][K] * BT[N][K]^T ----------------
__global__ __launch_bounds__(256) void k_gemm(
    const f16* __restrict__ A, const f16* __restrict__ BT,
    int M, int N, int K, int mode,
    f16* __restrict__ Qo, f16* __restrict__ Ko, f16* __restrict__ Vt,
    const float* __restrict__ bias, float* __restrict__ out) {
  __shared__ f16 As[128 * 32];
  __shared__ f16 Bs[128 * 32];
  int tid = threadIdx.x;
  int wv = tid >> 6;
  int lane = tid & 63;
  int lr = lane & 15, lc = lane >> 4;
  int m0 = blockIdx.x * 128, n0 = blockIdx.y * 128;
  int wm = (wv >> 1) * 64, wn = (wv & 1) * 64;
  f32x4 acc[4][4] = {};
  int nK = K >> 5;
  for (int kt = 0; kt < nK; ++kt) {
    int k0 = kt << 5;
#pragma unroll
    for (int i = 0; i < 2; ++i) {
      int g = i * 256 + tid;
      gload_lds16(A + (size_t)(m0 + (g >> 2)) * K + k0 + (g & 3) * 8,
                  As + (size_t)(i * 256 + (tid & 192)) * 8);
    }
#pragma unroll
    for (int i = 0; i < 2; ++i) {
      int g = i * 256 + tid;
      gload_lds16(BT + (size_t)(n0 + (g >> 2)) * K + k0 + (g & 3) * 8,
                  Bs + (size_t)(i * 256 + (tid & 192)) * 8);
    }
    __syncthreads();
    f16x8 af[4], bf[4];
#pragma unroll
    for (int mi = 0; mi < 4; ++mi)
      af[mi] = *(const f16x8*)&As[(wm + mi * 16 + lr) * 32 + lc * 8];
#pragma unroll
    for (int ni = 0; ni < 4; ++ni)
      bf[ni] = *(const f16x8*)&Bs[(wn + ni * 16 + lr) * 32 + lc * 8];
#pragma unroll
    for (int mi = 0; mi < 4; ++mi)
#pragma unroll
      for (int ni = 0; ni < 4; ++ni)
        acc[mi][ni] = MFMA16(af[mi], bf[ni], acc[mi][ni]);
    __syncthreads();
  }
  if (mode == 0) {
#pragma unroll
    for (int ni = 0; ni < 4; ++ni) {
      int col = n0 + wn + ni * 16 + lr;
      int s = col / 768;
      int hh = (col - s * 768) >> 6;
      int d = col & 63;
      if (s == 2) {
#pragma unroll
        for (int mi = 0; mi < 4; ++mi) {
          int row0 = m0 + wm + mi * 16 + lc * 4;
          int b = row0 >> 11, t = row0 & 2047;
          f16x4 tv;
#pragma unroll
          for (int r = 0; r < 4; ++r) tv[r] = (f16)acc[mi][ni][r];
          *(f16x4*)&Vt[((size_t)(b * 12 + hh) * 64 + d) * 2048 + t] = tv;
        }
      } else {
        f16* dst = (s == 0) ? Qo : Ko;
#pragma unroll
        for (int mi = 0; mi < 4; ++mi)
#pragma unroll
          for (int r = 0; r < 4; ++r) {
            int row = m0 + wm + mi * 16 + lc * 4 + r;
            int b = row >> 11, t = row & 2047;
            dst[((size_t)(b * 12 + hh) * 2048 + t) * 64 + d] =
                (f16)acc[mi][ni][r];
          }
      }
    }
  } else {
#pragma unroll
    for (int ni = 0; ni < 4; ++ni) {
      int col = n0 + wn + ni * 16 + lr;
      float bv = bias[col];
#pragma unroll
      for (int mi = 0; mi < 4; ++mi)
#pragma unroll
        for (int r = 0; r < 4; ++r) {
          int row = m0 + wm + mi * 16 + lc * 4 + r;
          out[(size_t)row * 768 + col] = acc[mi][ni][r] + bv;
        }
    }
  }
}

// ---- causal softplus-normalized attention: row-split pairs, uniform blocks ----
// Block (bh, y): p = y>>1, hf = y&1. Owns rows [qt*32+hf*16, +16) of qt=p AND
// qt=63-p. Tile list = [nA tiles of A] ++ [nB of B], nA+nB == 33 for every
// block. 4 waves stride the list (idx = wv, wv+4, ...). Per phase: private
// o/rowsum, LDS combine. Grid 24x64 = 1536 uniform blocks.
__global__ __launch_bounds__(256) void k_attn(const f16* __restrict__ Q,
                                              const f16* __restrict__ K,
                                              const f16* __restrict__ Vt,
                                              f16* __restrict__ Ab) {
  __shared__ __align__(16) char smem[17664];
  // k-loop phase: per-wave P tile [16 rows][64 keys] f16, XOR-swizzled (2KB ea)
  // combine phase: comb[4][16][68] f32 (17408B) + rs[4][16] (256B)
  float (*comb)[16][68] = (float(*)[16][68])smem;
  float* rscomb = (float*)(smem + 17408);
  int tid = threadIdx.x, wv = tid >> 6, lane = tid & 63;
  int lr = lane & 15, lc = lane >> 4;
  int bh = blockIdx.x;
  int p = blockIdx.y >> 1, hf = blockIdx.y & 1;
  int b = bh / 12, hh = bh - b * 12;
  const f16* Qp = Q + (size_t)bh * 2048 * 64;
  const f16* Kp = K + (size_t)bh * 2048 * 64;
  const f16* Vp = Vt + (size_t)bh * 64 * 2048;
  char* wb = smem + wv * 2048;  // this wave's P tile (byte base)

  // XOR-swizzled P addressing (identical layout to r5, 1 xor per access):
  // write f16-idx = B0 ^ (r<<6) ^ ((r ^ (ni<<1))<<3);  B0,X in bytes below
  int S0 = (lr >> 3) | ((lc & 1) << 2);
  int wB = (lc * 256 + (S0 << 3) + (lr & 7)) * 2;          // write base (bytes)
  int rB = (lr * 64 + ((lr & 7) << 3)) * 2;                // read base (bytes)

  const f16 a16 = (f16)0.18033688f;  // 0.125 * log2(e): fold scale into Q

  f16x8 qf[2];
  f32x4 o[4];
  float rsl[4];

  // w' = log2(1+2^z); uniform ln2 factor cancels in w/rowsum.
  auto do_tile = [&](int qw, int kb, bool maskit) {
    f16x8 vf[2][4];  // hoisted V: latency hides under QK^T + softplus
#pragma unroll
    for (int kh = 0; kh < 2; ++kh)
#pragma unroll
      for (int di = 0; di < 4; ++di)
        vf[kh][di] = *(const f16x8*)&Vp[(size_t)(di * 16 + lr) * 2048 + kb +
                                        kh * 32 + lc * 8];
    f32x4 s[4] = {};
#pragma unroll
    for (int ni = 0; ni < 4; ++ni)
#pragma unroll
      for (int kh = 0; kh < 2; ++kh) {
        f16x8 kf = *(const f16x8*)&Kp[(size_t)(kb + ni * 16 + lr) * 64 +
                                      kh * 32 + lc * 8];
        s[ni] = MFMA16(qf[kh], kf, s[ni]);
      }
#pragma unroll
    for (int ni = 0; ni < 4; ++ni) {
#pragma unroll
      for (int r = 0; r < 4; ++r) {
        float z = s[ni][r];
        float w = __builtin_amdgcn_logf(1.f + __builtin_amdgcn_exp2f(z));
        if (maskit)
          w = (kb + ni * 16 + lr <= qw + lc * 4 + r) ? w : 0.f;
        rsl[r] += w;
        int xo = ((r << 6) ^ ((r ^ (ni << 1)) << 3)) * 2;  // compile-time const
        *(f16*)(wb + (wB ^ xo)) = (f16)w;
      }
    }
#pragma unroll
    for (int kh = 0; kh < 2; ++kh) {
      f16x8 pa = *(const f16x8*)(wb + (rB ^ ((((kh << 2) | lc) << 3) * 2)));
#pragma unroll
      for (int di = 0; di < 4; ++di)
        o[di] = MFMA16(pa, vf[kh][di], o[di]);
    }
  };

  auto run_phase = [&](int qt, int i0, int iend, int nskip, int diagIdx) {
    int qw = qt * 32 + hf * 16;
#pragma unroll
    for (int kh = 0; kh < 2; ++kh) {
      qf[kh] = *(const f16x8*)&Qp[(size_t)(qw + lr) * 64 + kh * 32 + lc * 8];
      qf[kh] *= a16;
    }
#pragma unroll
    for (int di = 0; di < 4; ++di) o[di] = (f32x4){0.f, 0.f, 0.f, 0.f};
#pragma unroll
    for (int r = 0; r < 4; ++r) rsl[r] = 0.f;
    for (int i = i0; i < iend; i += 4)
      do_tile(qw, (i - nskip) << 6, i == diagIdx);
    // rowsum reduce across the 16 lr lanes
#pragma unroll
    for (int r = 0; r < 4; ++r) {
      float s1 = rsl[r];
      s1 += __shfl_xor(s1, 1);
      s1 += __shfl_xor(s1, 2);
      s1 += __shfl_xor(s1, 4);
      s1 += __shfl_xor(s1, 8);
      rsl[r] = s1;
    }
    __syncthreads();  // all waves done with P tiles; smem becomes comb
#pragma unroll
    for (int r = 0; r < 4; ++r) {
      int row = lc * 4 + r;
      if (lr == 0) rscomb[wv * 16 + row] = rsl[r];
#pragma unroll
      for (int di = 0; di < 4; ++di)
        comb[wv][row][di * 16 + lr] = o[di][r];
    }
    __syncthreads();
    // combine: thread -> (row, 4 d's); normalize; store f16
    int row = tid >> 4, d0 = (tid & 15) << 2;
    float inv = 1.0f / (rscomb[row] + rscomb[16 + row] + rscomb[32 + row] +
                        rscomb[48 + row]);
    float4 a0 = *(const float4*)&comb[0][row][d0];
    float4 a1 = *(const float4*)&comb[1][row][d0];
    float4 a2 = *(const float4*)&comb[2][row][d0];
    float4 a3 = *(const float4*)&comb[3][row][d0];
    f16x4 o4;
    o4[0] = (f16)((a0.x + a1.x + a2.x + a3.x) * inv);
    o4[1] = (f16)((a0.y + a1.y + a2.y + a3.y) * inv);
    o4[2] = (f16)((a0.z + a1.z + a2.z + a3.z) * inv);
    o4[3] = (f16)((a0.w + a1.w + a2.w + a3.w) * inv);
    *(f16x4*)&Ab[((size_t)b * 2048 + qw + row) * 768 + hh * 64 + d0] = o4;
    __syncthreads();  // combine reads done before next phase reuses P tiles
  };

  int qtA = p, qtB = 63 - p;
  int nA = (qtA >> 1) + 1;  // tiles for phase A (same for both row halves)
  // phase A: list indices [0, nA)
  run_phase(qtA, wv, nA, 0, nA - 1);
  // phase B: list indices [nA, 33); this wave resumes at first own index >= nA
  int d = nA - wv;
  int iB = wv + ((d > 0) ? ((d + 3) & ~3) : 0);
  run_phase(qtB, iB, 33, nA, 32);
}

// ---------------- host ----------------
extern "C" void kernel_launch(void* const* d_in, const int* in_sizes, int n_in,
                              void* d_out, int out_size, void* d_ws,
                              size_t ws_size, hipStream_t stream) {
  const float* x = (const float*)d_in[0];
  const float* Wqkv = (const float*)d_in[1];
  const float* Wproj = (const float*)d_in[2];
  const float* bproj = (const float*)d_in[3];
  float* out = (float*)d_out;
  char* ws = (char*)d_ws;

  f16* xb     = (f16*)(ws + 0);         // 4096x768
  f16* WqkvT  = (f16*)(ws + 6291456);   // 2304x768
  f16* WprojT = (f16*)(ws + 9830400);   // 768x768
  f16* Qb     = (f16*)(ws + 11010048);  // 24x2048x64
  f16* Kb     = (f16*)(ws + 17301504);  // 24x2048x64
  f16* Vtb    = (f16*)(ws + 23592960);  // 24x64x2048
  f16* Ab     = (f16*)(ws + 29884416);  // 4096x768
  // total 36,175,872 B

  k_prep<<<1344, 256, 0, stream>>>(x, xb, Wqkv, WqkvT, Wproj, WprojT);
  k_gemm<<<dim3(32, 18), 256, 0, stream>>>(xb, WqkvT, 4096, 2304, 768, 0, Qb,
                                           Kb, Vtb, nullptr, nullptr);
  k_attn<<<dim3(24, 64), 256, 0, stream>>>(Qb, Kb, Vtb, Ab);
  k_gemm<<<dim3(32, 6), 256, 0, stream>>>(Ab, WprojT, 4096, 768, 768, 1,
                                          nullptr, nullptr, nullptr, bproj, out);
}

// Round 8
// 124.737 us; speedup vs baseline: 1.3469x; 1.3469x over previous
//
#include <hip/hip_runtime.h>

typedef _Float16 f16;
typedef __attribute__((ext_vector_type(4))) _Float16 f16x4;
typedef __attribute__((ext_vector_type(8))) _Float16 f16x8;
typedef __attribute__((ext_vector_type(4))) float f32x4;

#define MFMA16(a, b, c) __builtin_amdgcn_mfma_f32_16x16x32_f16((a), (b), (c), 0, 0, 0)

__device__ __forceinline__ void gload_lds16(const void* g, void* l) {
  __builtin_amdgcn_global_load_lds(
      (const __attribute__((address_space(1))) void*)g,
      (__attribute__((address_space(3))) void*)l, 16, 0, 0);
}

// ------- fused prep: convert x -> f16, transpose Wqkv & Wproj -> [N][K] f16 -------
__global__ __launch_bounds__(256) void k_prep(
    const float* __restrict__ x, f16* __restrict__ xb,
    const float* __restrict__ Wq, f16* __restrict__ WqT,
    const float* __restrict__ Wp, f16* __restrict__ WpT) {
  __shared__ float tile[64][65];
  int bid = blockIdx.x;
  if (bid < 768) {
    int i = bid * 256 + threadIdx.x;
#pragma unroll
    for (int it = 0; it < 4; ++it, i += 768 * 256) {
      float4 v = ((const float4*)x)[i];
      f16x4 o;
      o[0] = (f16)v.x; o[1] = (f16)v.y; o[2] = (f16)v.z; o[3] = (f16)v.w;
      ((f16x4*)xb)[i] = o;
    }
    return;
  }
  const float* in; f16* out; int N, n0, k0;
  if (bid < 1200) {
    int t = bid - 768;
    in = Wq; out = WqT; N = 2304;
    n0 = (t % 36) * 64; k0 = (t / 36) * 64;
  } else {
    int t = bid - 1200;
    in = Wp; out = WpT; N = 768;
    n0 = (t % 12) * 64; k0 = (t / 12) * 64;
  }
  int c = threadIdx.x & 63, r4 = threadIdx.x >> 6;
#pragma unroll
  for (int i = 0; i < 16; ++i) {
    int r = i * 4 + r4;
    tile[r][c] = in[(size_t)(k0 + r) * N + n0 + c];
  }
  __syncthreads();
#pragma unroll
  for (int i = 0; i < 16; ++i) {
    int r = i * 4 + r4;
    out[(size_t)(n0 + r) * 768 + k0 + c] = (f16)tile[c][r];
  }
}

// ---------------- 128x128 f16 MFMA GEMM, A[M][K] * BT[N][K]^T ----------------
__global__ __launch_bounds__(256) void k_gemm(
    const f16* __restrict__ A, const f16* __restrict__ BT,
    int M, int N, int K, int mode,
    f16* __restrict__ Qo, f16* __restrict__ Ko, f16* __restrict__ Vt,
    const float* __restrict__ bias, float* __restrict__ out) {
  __shared__ f16 As[128 * 32];
  __shared__ f16 Bs[128 * 32];
  int tid = threadIdx.x;
  int wv = tid >> 6;
  int lane = tid & 63;
  int lr = lane & 15, lc = lane >> 4;
  int m0 = blockIdx.x * 128, n0 = blockIdx.y * 128;
  int wm = (wv >> 1) * 64, wn = (wv & 1) * 64;
  f32x4 acc[4][4] = {};
  int nK = K >> 5;
  for (int kt = 0; kt < nK; ++kt) {
    int k0 = kt << 5;
#pragma unroll
    for (int i = 0; i < 2; ++i) {
      int g = i * 256 + tid;
      gload_lds16(A + (size_t)(m0 + (g >> 2)) * K + k0 + (g & 3) * 8,
                  As + (size_t)(i * 256 + (tid & 192)) * 8);
    }
#pragma unroll
    for (int i = 0; i < 2; ++i) {
      int g = i * 256 + tid;
      gload_lds16(BT + (size_t)(n0 + (g >> 2)) * K + k0 + (g & 3) * 8,
                  Bs + (size_t)(i * 256 + (tid & 192)) * 8);
    }
    __syncthreads();
    f16x8 af[4], bf[4];
#pragma unroll
    for (int mi = 0; mi < 4; ++mi)
      af[mi] = *(const f16x8*)&As[(wm + mi * 16 + lr) * 32 + lc * 8];
#pragma unroll
    for (int ni = 0; ni < 4; ++ni)
      bf[ni] = *(const f16x8*)&Bs[(wn + ni * 16 + lr) * 32 + lc * 8];
#pragma unroll
    for (int mi = 0; mi < 4; ++mi)
#pragma unroll
      for (int ni = 0; ni < 4; ++ni)
        acc[mi][ni] = MFMA16(af[mi], bf[ni], acc[mi][ni]);
    __syncthreads();
  }
  if (mode == 0) {
#pragma unroll
    for (int ni = 0; ni < 4; ++ni) {
      int col = n0 + wn + ni * 16 + lr;
      int s = col / 768;
      int hh = (col - s * 768) >> 6;
      int d = col & 63;
      if (s == 2) {
#pragma unroll
        for (int mi = 0; mi < 4; ++mi) {
          int row0 = m0 + wm + mi * 16 + lc * 4;
          int b = row0 >> 11, t = row0 & 2047;
          f16x4 tv;
#pragma unroll
          for (int r = 0; r < 4; ++r) tv[r] = (f16)acc[mi][ni][r];
          *(f16x4*)&Vt[((size_t)(b * 12 + hh) * 64 + d) * 2048 + t] = tv;
        }
      } else {
        f16* dst = (s == 0) ? Qo : Ko;
#pragma unroll
        for (int mi = 0; mi < 4; ++mi)
#pragma unroll
          for (int r = 0; r < 4; ++r) {
            int row = m0 + wm + mi * 16 + lc * 4 + r;
            int b = row >> 11, t = row & 2047;
            dst[((size_t)(b * 12 + hh) * 2048 + t) * 64 + d] =
                (f16)acc[mi][ni][r];
          }
      }
    }
  } else {
#pragma unroll
    for (int ni = 0; ni < 4; ++ni) {
      int col = n0 + wn + ni * 16 + lr;
      float bv = bias[col];
#pragma unroll
      for (int mi = 0; mi < 4; ++mi)
#pragma unroll
        for (int r = 0; r < 4; ++r) {
          int row = m0 + wm + mi * 16 + lc * 4 + r;
          out[(size_t)row * 768 + col] = acc[mi][ni][r] + bv;
        }
    }
  }
}

// ------------- causal softplus-normalized attention, K-pipelined -------------
// r5 structure: one 256-thread block per (bh, 32-row q-tile), 4 waves stride
// k-tiles (kt = wv, wv+4, ...), private O/rowsum, LDS combine at the end.
// New: K fragments live in a persistent register buffer; next tile's K loads
// issue under the current tile's softplus+PV (the dominant stall in r5).
__global__ __launch_bounds__(256) void k_attn(const f16* __restrict__ Q,
                                              const f16* __restrict__ K,
                                              const f16* __restrict__ Vt,
                                              f16* __restrict__ Ab) {
  __shared__ __align__(16) char smem[35328];
  // k-loop phase: per-wave P tile [32][64] f16 XOR-swizzled (4KB each)
  // combine phase (union): comb[4][32][68] f32 + rscomb[4][32]
  float (*comb)[32][68] = (float(*)[32][68])smem;
  float* rscomb = (float*)(smem + 34816);
  int tid = threadIdx.x, wv = tid >> 6, lane = tid & 63;
  int lr = lane & 15, lc = lane >> 4;
  int bh = blockIdx.x;
  int qt = 63 - blockIdx.y;  // heavy blocks dispatch first
  int qw = qt * 32;
  int b = bh / 12, h = bh - b * 12;
  const f16* Qp = Q + (size_t)bh * 2048 * 64;
  const f16* Kp = K + (size_t)bh * 2048 * 64;
  const f16* Vp = Vt + (size_t)bh * 64 * 2048;
  char* sb = smem;

  // XOR-swizzled P addressing, bit-exact to r5's layout, 1 XOR per access:
  //  write byte = WB ^ ((mi<<11)^(r<<7)^(r<<4)^(ni<<5))
  //  read  byte = RB ^ ((mi<<11)|(kh<<6))
  int WB = wv * 4096 + (lr << 1) + ((lc & 1) << 6) + (lc << 9);
  int RB = wv * 4096 + (lr << 7) + (((lr & 7) ^ lc) << 4);

  const f16 a16 = (f16)0.18033688f;  // 0.125 * log2(e): fold scale into Q
  f16x8 qf[2][2];
#pragma unroll
  for (int mi = 0; mi < 2; ++mi)
#pragma unroll
    for (int kh = 0; kh < 2; ++kh) {
      qf[mi][kh] = *(const f16x8*)&Qp[(size_t)(qw + mi * 16 + lr) * 64 +
                                      kh * 32 + lc * 8];
      qf[mi][kh] *= a16;
    }

  f32x4 o[2][4] = {};
  float rsl[2][4] = {};
  f16x8 kA[2][4];  // persistent K fragment buffer [kh][ni]

  auto loadK = [&](int kb) {
#pragma unroll
    for (int kh = 0; kh < 2; ++kh)
#pragma unroll
      for (int ni = 0; ni < 4; ++ni)
        kA[kh][ni] = *(const f16x8*)&Kp[(size_t)(kb + ni * 16 + lr) * 64 +
                                        kh * 32 + lc * 8];
  };

  // w' = log2(1+2^z); the uniform ln2 factor cancels in w/rowsum.
  auto do_tile = [&](int kb, int kbn, bool maskit) {
    // 1. QK^T consumes kA (loaded one tile ago)
    f32x4 s[2][4] = {};
#pragma unroll
    for (int ni = 0; ni < 4; ++ni)
#pragma unroll
      for (int kh = 0; kh < 2; ++kh) {
        s[0][ni] = MFMA16(qf[0][kh], kA[kh][ni], s[0][ni]);
        s[1][ni] = MFMA16(qf[1][kh], kA[kh][ni], s[1][ni]);
      }
    // 2. V loads for this tile (latency hides under softplus)
    f16x8 vf[2][4];
#pragma unroll
    for (int kh = 0; kh < 2; ++kh)
#pragma unroll
      for (int di = 0; di < 4; ++di)
        vf[kh][di] = *(const f16x8*)&Vp[(size_t)(di * 16 + lr) * 2048 + kb +
                                        kh * 32 + lc * 8];
    // 3. prefetch next tile's K (latency hides under softplus+PV)
    if (kbn >= 0) loadK(kbn);
    // 4. softplus + rowsum + swizzled LDS write
#pragma unroll
    for (int mi = 0; mi < 2; ++mi)
#pragma unroll
      for (int ni = 0; ni < 4; ++ni)
#pragma unroll
        for (int r = 0; r < 4; ++r) {
          float z = s[mi][ni][r];
          float w = __builtin_amdgcn_logf(1.f + __builtin_amdgcn_exp2f(z));
          if (maskit)
            w = (kb + ni * 16 + lr <= qw + mi * 16 + lc * 4 + r) ? w : 0.f;
          rsl[mi][r] += w;
          int XO = (mi << 11) ^ (r << 7) ^ (r << 4) ^ (ni << 5);
          *(f16*)(sb + (WB ^ XO)) = (f16)w;
        }
    // 5. PV
#pragma unroll
    for (int kh = 0; kh < 2; ++kh) {
      f16x8 pa0 = *(const f16x8*)(sb + (RB ^ (kh << 6)));
      f16x8 pa1 = *(const f16x8*)(sb + (RB ^ ((1 << 11) | (kh << 6))));
#pragma unroll
      for (int di = 0; di < 4; ++di) {
        o[0][di] = MFMA16(pa0, vf[kh][di], o[0][di]);
        o[1][di] = MFMA16(pa1, vf[kh][di], o[1][di]);
      }
    }
  };

  int dt = qw >> 6;  // diagonal tile index
  int nfull = (dt > wv) ? ((dt - wv + 3) >> 2) : 0;
  bool owndiag = ((dt & 3) == wv);
  if (nfull > 0 || owndiag) loadK(nfull > 0 ? wv * 64 : dt * 64);
  for (int i = 0; i < nfull; ++i) {
    int kb = (wv + 4 * i) * 64;
    int kbn = (i + 1 < nfull) ? kb + 256 : (owndiag ? dt * 64 : -1);
    do_tile(kb, kbn, false);
  }
  if (owndiag) do_tile(dt * 64, -1, true);

  // intra-wave rowsum reduce across the 16 lr lanes
#pragma unroll
  for (int mi = 0; mi < 2; ++mi)
#pragma unroll
    for (int r = 0; r < 4; ++r) {
      float p = rsl[mi][r];
      p += __shfl_xor(p, 1);
      p += __shfl_xor(p, 2);
      p += __shfl_xor(p, 4);
      p += __shfl_xor(p, 8);
      rsl[mi][r] = p;
    }

  __syncthreads();  // all waves done with P tiles; smem becomes comb

#pragma unroll
  for (int mi = 0; mi < 2; ++mi)
#pragma unroll
    for (int r = 0; r < 4; ++r) {
      int row = mi * 16 + lc * 4 + r;
      if (lr == 0) rscomb[wv * 32 + row] = rsl[mi][r];
#pragma unroll
      for (int di = 0; di < 4; ++di)
        comb[wv][row][di * 16 + lr] = o[mi][di][r];
    }
  __syncthreads();

  // cross-wave combine: thread -> (row, 8 d's); normalize; store f16
  int row = tid >> 3, d0 = (tid & 7) << 3;
  float inv = 1.0f / (rscomb[row] + rscomb[32 + row] + rscomb[64 + row] +
                      rscomb[96 + row]);
  float sum[8] = {};
#pragma unroll
  for (int w = 0; w < 4; ++w) {
    float4 a = *(const float4*)&comb[w][row][d0];
    float4 c = *(const float4*)&comb[w][row][d0 + 4];
    sum[0] += a.x; sum[1] += a.y; sum[2] += a.z; sum[3] += a.w;
    sum[4] += c.x; sum[5] += c.y; sum[6] += c.z; sum[7] += c.w;
  }
  f16x8 o8;
#pragma unroll
  for (int e = 0; e < 8; ++e) o8[e] = (f16)(sum[e] * inv);
  *(f16x8*)&Ab[((size_t)b * 2048 + qw + row) * 768 + h * 64 + d0] = o8;
}

// ---------------- host ----------------
extern "C" void kernel_launch(void* const* d_in, const int* in_sizes, int n_in,
                              void* d_out, int out_size, void* d_ws,
                              size_t ws_size, hipStream_t stream) {
  const float* x = (const float*)d_in[0];
  const float* Wqkv = (const float*)d_in[1];
  const float* Wproj = (const float*)d_in[2];
  const float* bproj = (const float*)d_in[3];
  float* out = (float*)d_out;
  char* ws = (char*)d_ws;

  f16* xb     = (f16*)(ws + 0);         // 4096x768
  f16* WqkvT  = (f16*)(ws + 6291456);   // 2304x768
  f16* WprojT = (f16*)(ws + 9830400);   // 768x768
  f16* Qb     = (f16*)(ws + 11010048);  // 24x2048x64
  f16* Kb     = (f16*)(ws + 17301504);  // 24x2048x64
  f16* Vtb    = (f16*)(ws + 23592960);  // 24x64x2048
  f16* Ab     = (f16*)(ws + 29884416);  // 4096x768
  // total 36,175,872 B

  k_prep<<<1344, 256, 0, stream>>>(x, xb, Wqkv, WqkvT, Wproj, WprojT);
  k_gemm<<<dim3(32, 18), 256, 0, stream>>>(xb, WqkvT, 4096, 2304, 768, 0, Qb,
                                           Kb, Vtb, nullptr, nullptr);
  k_attn<<<dim3(24, 64), 256, 0, stream>>>(Qb, Kb, Vtb, Ab);
  k_gemm<<<dim3(32, 6), 256, 0, stream>>>(Ab, WprojT, 4096, 768, 768, 1,
                                          nullptr, nullptr, nullptr, bproj, out);
}